// Round 7
// baseline (377.287 us; speedup 1.0000x reference)
//
#include <hip/hip_runtime.h>
#include <hip/hip_bf16.h>

#define NN 100000
#define EE 1600000
#define ETOT (EE + NN)          // 1,700,000 edges incl. self-loops
#define IND 32
#define HIDD 64
#define NHEADS 4
#define OUTD 32
#define HID2D 32

#define BSH 9                   // 512 nodes per bucket
#define NBUCK 196               // ceil(NN / 512)
#define CAP 10240               // max edges per bucket (mean ~8675)
#define EPB 2048                // edges per k_bin block

typedef unsigned int uint;

__device__ __forceinline__ uint pack2(float a, float b) {
  uint lo = (uint)__bfloat16_as_ushort(__float2bfloat16(a));
  uint hi = (uint)__bfloat16_as_ushort(__float2bfloat16(b));
  return (hi << 16) | lo;
}
__device__ __forceinline__ float lo2f(uint w) { return __uint_as_float(w << 16); }
__device__ __forceinline__ float hi2f(uint w) { return __uint_as_float(w & 0xFFFF0000u); }

// ---------- linear 1: h1(bf16) = x @ W1 ; as1/ad1 f32 attention dots ----------
__global__ __launch_bounds__(256) void k_lin1(
    const float* __restrict__ x, const float* __restrict__ W1,
    const float* __restrict__ atsrc, const float* __restrict__ atdst,
    uint* __restrict__ h1u, float* __restrict__ as1, float* __restrict__ ad1) {
  __shared__ float Ws[IND * HIDD];
  __shared__ float xs[8 * IND];
  __shared__ float atS[HIDD], atD[HIDD];
  int t = threadIdx.x;
  for (int i = t; i < IND * HIDD; i += 256) Ws[i] = W1[i];
  if (t < HIDD) { atS[t] = atsrc[t]; atD[t] = atdst[t]; }
  xs[t] = x[blockIdx.x * 256 + t];
  __syncthreads();
  int nl = t >> 5, tl = t & 31;
  int node = blockIdx.x * 8 + nl;
  int j0 = 2 * tl, j1 = j0 + 1;
  float a0 = 0.f, a1 = 0.f;
#pragma unroll
  for (int k = 0; k < IND; k++) {
    float xv = xs[nl * IND + k];
    a0 += xv * Ws[k * HIDD + j0];
    a1 += xv * Ws[k * HIDD + j1];
  }
  h1u[node * 32 + tl] = pack2(a0, a1);
  float ps = a0 * atS[j0] + a1 * atS[j1];
  float pd = a0 * atD[j0] + a1 * atD[j1];
#pragma unroll
  for (int off = 4; off >= 1; off >>= 1) {
    ps += __shfl_down(ps, off, 8);
    pd += __shfl_down(pd, off, 8);
  }
  if ((tl & 7) == 0) {
    as1[node * NHEADS + (tl >> 3)] = ps;
    ad1[node * NHEADS + (tl >> 3)] = pd;
  }
}

// ---------- pass 1: bucket edges by dst>>9; record = (src<<9)|(dst&511) ----------
__global__ __launch_bounds__(256) void k_bin(const int* __restrict__ ei,
                                             int* __restrict__ bcur,
                                             int* __restrict__ bins) {
  __shared__ int cnt[NBUCK];
  int t = threadIdx.x;
  for (int i = t; i < NBUCK; i += 256) cnt[i] = 0;
  __syncthreads();
  int base = blockIdx.x * EPB;
  int recs[8], bks[8];
#pragma unroll
  for (int k = 0; k < 8; k++) {
    int i = base + k * 256 + t;
    recs[k] = -1; bks[k] = 0;
    if (i < ETOT) {
      int s, d;
      if (i < EE) { s = ei[i]; d = ei[EE + i]; } else { s = i - EE; d = s; }
      recs[k] = (s << BSH) | (d & ((1 << BSH) - 1));
      bks[k] = d >> BSH;
      atomicAdd(&cnt[bks[k]], 1);
    }
  }
  __syncthreads();
  for (int i = t; i < NBUCK; i += 256) cnt[i] = atomicAdd(&bcur[i], cnt[i]);
  __syncthreads();
#pragma unroll
  for (int k = 0; k < 8; k++) {
    if (recs[k] >= 0) {
      int pos = atomicAdd(&cnt[bks[k]], 1);
      bins[bks[k] * CAP + pos] = recs[k];
    }
  }
}

// ---------- pass 2: per-bucket local CSR, with inline 196-scan ----------
__global__ __launch_bounds__(256) void k_csr(const int* __restrict__ bcur,
                                             const int* __restrict__ bins,
                                             int* __restrict__ rowp,
                                             int* __restrict__ srcs) {
  __shared__ int lrec[CAP];
  __shared__ int ldeg[512], sA[512], sB[512];
  int b = blockIdx.x, t = threadIdx.x;
  // inline exclusive scan of the 196 bucket counts (redundant per block, cheap)
  {
    int v = (t < NBUCK) ? bcur[t] : 0;
    sA[t] = v;
    if (t >= 256) sA[t] = 0;
  }
  __syncthreads();
  int* in = sA; int* out = sB;
  for (int off = 1; off < 256; off <<= 1) {
    out[t] = in[t] + ((t >= off && t < 256) ? in[t - off] : 0);
    if (t >= 256) out[t] = 0;
    __syncthreads();
    int* tmp = in; in = out; out = tmp;
  }
  int gb = (b == 0) ? 0 : in[b - 1];
  if (b == 0 && t == 0) rowp[NN] = ETOT;
  __syncthreads();
  int count = bcur[b]; if (count > CAP) count = CAP;
  for (int i = t; i < 512; i += 256) ldeg[i] = 0;
  __syncthreads();
  for (int i = t; i < count; i += 256) {
    int r = bins[b * CAP + i];
    lrec[i] = r;
    atomicAdd(&ldeg[r & 511], 1);
  }
  __syncthreads();
  for (int i = t; i < 512; i += 256) sA[i] = ldeg[i];
  __syncthreads();
  in = sA; out = sB;
  for (int off = 1; off < 512; off <<= 1) {
    for (int i = t; i < 512; i += 256)
      out[i] = in[i] + ((i >= off) ? in[i - off] : 0);
    __syncthreads();
    int* tmp = in; in = out; out = tmp;
  }
  int nb = b << BSH;
  for (int i = t; i < 512; i += 256) {
    int ex = in[i] - ldeg[i];          // exclusive scan
    if (nb + i < NN) rowp[nb + i] = gb + ex;
    ldeg[i] = ex;                      // reuse as scatter cursor
  }
  __syncthreads();
  for (int i = t; i < count; i += 256) {
    int r = lrec[i];
    int pos = atomicAdd(&ldeg[r & 511], 1);
    srcs[gb + pos] = r >> BSH;
  }
}

// ---------- GAT1 agg + BN1 + ReLU  +  fused lin2 (h2 = hbn@W2, as2/ad2) ----------
// wave per node; 8 edge slots x 8 lanes; lane reads uint4 = 8 bf16 features.
__global__ __launch_bounds__(256) void k_agg1f(
    const int* __restrict__ rowp, const int* __restrict__ srcs,
    const uint* __restrict__ h1u, const float* __restrict__ as1,
    const float* __restrict__ ad1, const float* __restrict__ b1,
    const float* __restrict__ g, const float* __restrict__ bb,
    const float* __restrict__ m, const float* __restrict__ v,
    const float* __restrict__ W2, const float* __restrict__ atsrc2,
    const float* __restrict__ atdst2,
    uint* __restrict__ h2u, float* __restrict__ as2, float* __restrict__ ad2) {
  __shared__ float W2s[HIDD * OUTD];     // 8KB
  __shared__ float atS2s[OUTD], atD2s[OUTD];
  __shared__ float rowS[4][HIDD];
  int t = threadIdx.x;
  for (int i = t; i < HIDD * OUTD; i += 256) W2s[i] = W2[i];
  if (t < OUTD) { atS2s[t] = atsrc2[t]; atD2s[t] = atdst2[t]; }
  __syncthreads();
  int wid = t >> 6, lane = t & 63;
  int node = blockIdx.x * 4 + wid;
  int slot = lane >> 3;      // edge slot (8)
  int fl = lane & 7;         // feature group: feats fl*8..fl*8+7
  int hd = fl >> 1;
  int start = rowp[node], end = rowp[node + 1];
  int lastp = end - 1;       // deg >= 1 always (self-loop)
  float adv = ad1[node * NHEADS + hd];
  const uint4* h14 = (const uint4*)h1u;
  float acc[8] = {0.f, 0.f, 0.f, 0.f, 0.f, 0.f, 0.f, 0.f};
  float l = 0.f;
  int p = start + slot;
  int pc = p < lastp ? p : lastp;
  int s0 = srcs[pc];
  uint4 w = h14[s0 * 8 + fl];
  float as = as1[s0 * NHEADS + hd];
  int p1 = p + 8;
  int pc1 = p1 < lastp ? p1 : lastp;
  int s1 = srcs[pc1];
  while (p < end) {
    uint4 wn = h14[s1 * 8 + fl];
    float asn = as1[s1 * NHEADS + hd];
    int p2 = p1 + 8;
    int pc2 = p2 < lastp ? p2 : lastp;
    int s2 = srcs[pc2];
    float e = as + adv;
    e = fmaxf(e, 0.2f * e);
    float ex = __expf(e);
    l += ex;
    acc[0] += ex * lo2f(w.x); acc[1] += ex * hi2f(w.x);
    acc[2] += ex * lo2f(w.y); acc[3] += ex * hi2f(w.y);
    acc[4] += ex * lo2f(w.z); acc[5] += ex * hi2f(w.z);
    acc[6] += ex * lo2f(w.w); acc[7] += ex * hi2f(w.w);
    w = wn; as = asn; s1 = s2; p = p1; p1 = p2;
  }
#pragma unroll
  for (int off = 8; off <= 32; off <<= 1) {
#pragma unroll
    for (int i = 0; i < 8; i++) acc[i] += __shfl_xor(acc[i], off, 64);
    l += __shfl_xor(l, off, 64);
  }
  if (slot == 0) {
    float li = 1.f / (l + 1e-16f);
    int fb = fl * 8;
#pragma unroll
    for (int i = 0; i < 8; i++) {
      int j = fb + i;
      float ov = acc[i] * li + b1[j];
      ov = (ov - m[j]) * rsqrtf(v[j] + 1e-5f) * g[j] + bb[j];
      rowS[wid][j] = fmaxf(ov, 0.f);
    }
  }
  __syncthreads();
  // fused lin2: h2[j] = row @ W2[:,j]; lanes split the k-range by half
  int j = lane & 31, half = lane >> 5;
  float hv = 0.f;
#pragma unroll
  for (int k2 = 0; k2 < 32; k2++) {
    int k = half * 32 + k2;
    hv += rowS[wid][k] * W2s[k * OUTD + j];
  }
  hv += __shfl_xor(hv, 32, 64);        // both halves now hold full h2[j]
  float ps = hv * atS2s[j], pd = hv * atD2s[j];
#pragma unroll
  for (int off = 1; off <= 16; off <<= 1) {
    ps += __shfl_xor(ps, off, 64);     // stays within each 32-half
    pd += __shfl_xor(pd, off, 64);
  }
  if (lane == 0) { as2[node] = ps; ad2[node] = pd; }
  float hn = __shfl_down(hv, 1, 64);   // h2[j+1] for even j in lower half
  if (half == 0 && (j & 1) == 0) h2u[node * 16 + (j >> 1)] = pack2(hv, hn);
}

// ---------- GAT2 agg + BN2 + ReLU + emb store  +  fused classifier/regressor ----------
// wave per node; 8 edge slots x 8 lanes; lane reads uint2 = 4 bf16 features.
__global__ __launch_bounds__(256) void k_agg2f(
    const int* __restrict__ rowp, const int* __restrict__ srcs,
    const uint* __restrict__ h2u, const float* __restrict__ as2,
    const float* __restrict__ ad2, const float* __restrict__ b2v,
    const float* __restrict__ g, const float* __restrict__ bb,
    const float* __restrict__ m, const float* __restrict__ v,
    const float* __restrict__ cw1, const float* __restrict__ cb1,
    const float* __restrict__ cw2, const float* __restrict__ cb2,
    const float* __restrict__ rw1, const float* __restrict__ rb1,
    const float* __restrict__ rw2, const float* __restrict__ rb2,
    float* __restrict__ out_emb, float* __restrict__ out_roles,
    float* __restrict__ out_energy) {
  __shared__ float C1s[OUTD * HID2D], R1s[OUTD * HID2D];   // 4KB + 4KB
  __shared__ float C2s[HID2D * 3], R2s[HID2D], CB1s[HID2D], RB1s[HID2D];
  __shared__ float cb2s[3], rb2s[1];
  __shared__ float rowE[4][OUTD];
  int t = threadIdx.x;
  for (int i = t; i < OUTD * HID2D; i += 256) { C1s[i] = cw1[i]; R1s[i] = rw1[i]; }
  if (t < HID2D) { CB1s[t] = cb1[t]; RB1s[t] = rb1[t]; R2s[t] = rw2[t]; }
  if (t < HID2D * 3) C2s[t] = cw2[t];
  if (t < 3) cb2s[t] = cb2[t];
  if (t == 0) rb2s[0] = rb2[0];
  __syncthreads();
  int wid = t >> 6, lane = t & 63;
  int node = blockIdx.x * 4 + wid;
  int slot = lane >> 3;
  int fl = lane & 7;         // feats fl*4..fl*4+3
  int start = rowp[node], end = rowp[node + 1];
  int lastp = end - 1;
  float adv = ad2[node];
  const uint2* h22 = (const uint2*)h2u;
  float acc[4] = {0.f, 0.f, 0.f, 0.f};
  float l = 0.f;
  int p = start + slot;
  int pc = p < lastp ? p : lastp;
  int s0 = srcs[pc];
  uint2 w = h22[s0 * 8 + fl];
  float as = as2[s0];
  int p1 = p + 8;
  int pc1 = p1 < lastp ? p1 : lastp;
  int s1 = srcs[pc1];
  while (p < end) {
    uint2 wn = h22[s1 * 8 + fl];
    float asn = as2[s1];
    int p2 = p1 + 8;
    int pc2 = p2 < lastp ? p2 : lastp;
    int s2 = srcs[pc2];
    float e = as + adv;
    e = fmaxf(e, 0.2f * e);
    float ex = __expf(e);
    l += ex;
    acc[0] += ex * lo2f(w.x); acc[1] += ex * hi2f(w.x);
    acc[2] += ex * lo2f(w.y); acc[3] += ex * hi2f(w.y);
    w = wn; as = asn; s1 = s2; p = p1; p1 = p2;
  }
#pragma unroll
  for (int off = 8; off <= 32; off <<= 1) {
#pragma unroll
    for (int i = 0; i < 4; i++) acc[i] += __shfl_xor(acc[i], off, 64);
    l += __shfl_xor(l, off, 64);
  }
  if (slot == 0) {
    float li = 1.f / (l + 1e-16f);
    int fb = fl * 4;
    float o[4];
#pragma unroll
    for (int i = 0; i < 4; i++) {
      int j = fb + i;
      float ov = acc[i] * li + b2v[j];
      ov = (ov - m[j]) * rsqrtf(v[j] + 1e-5f) * g[j] + bb[j];
      o[i] = fmaxf(ov, 0.f);
      rowE[wid][j] = o[i];
    }
    *(float4*)(out_emb + node * OUTD + fb) = make_float4(o[0], o[1], o[2], o[3]);
  }
  __syncthreads();
  // fused heads: lanes 0-31 classifier hidden j, lanes 32-63 regressor hidden j
  int j = lane & 31, half = lane >> 5;
  float a2 = half ? RB1s[j] : CB1s[j];
  const float* Wm = half ? R1s : C1s;
#pragma unroll
  for (int k = 0; k < OUTD; k++) a2 += rowE[wid][k] * Wm[k * HID2D + j];
  a2 = fmaxf(a2, 0.f);
  float p0, p1v, p2v;
  if (half == 0) {
    p0 = a2 * C2s[j * 3 + 0];
    p1v = a2 * C2s[j * 3 + 1];
    p2v = a2 * C2s[j * 3 + 2];
  } else {
    p0 = a2 * R2s[j];
    p1v = 0.f; p2v = 0.f;
  }
#pragma unroll
  for (int off = 1; off <= 16; off <<= 1) {   // stays within each 32-half
    p0 += __shfl_xor(p0, off, 64);
    p1v += __shfl_xor(p1v, off, 64);
    p2v += __shfl_xor(p2v, off, 64);
  }
  if (lane == 0) {
    out_roles[node * 3 + 0] = p0 + cb2s[0];
    out_roles[node * 3 + 1] = p1v + cb2s[1];
    out_roles[node * 3 + 2] = p2v + cb2s[2];
  }
  if (lane == 32) out_energy[node] = p0 + rb2s[0];
}

extern "C" void kernel_launch(void* const* d_in, const int* in_sizes, int n_in,
                              void* d_out, int out_size, void* d_ws, size_t ws_size,
                              hipStream_t stream) {
  const float* x    = (const float*)d_in[0];
  const int*   ei   = (const int*)d_in[1];
  const float* W1   = (const float*)d_in[2];
  const float* as1w = (const float*)d_in[3];
  const float* ad1w = (const float*)d_in[4];
  const float* b1   = (const float*)d_in[5];
  const float* W2   = (const float*)d_in[6];
  const float* as2w = (const float*)d_in[7];
  const float* ad2w = (const float*)d_in[8];
  const float* b2v  = (const float*)d_in[9];
  const float* bn1g = (const float*)d_in[10];
  const float* bn1b = (const float*)d_in[11];
  const float* bn1m = (const float*)d_in[12];
  const float* bn1v = (const float*)d_in[13];
  const float* bn2g = (const float*)d_in[14];
  const float* bn2b = (const float*)d_in[15];
  const float* bn2m = (const float*)d_in[16];
  const float* bn2v = (const float*)d_in[17];
  const float* cw1  = (const float*)d_in[18];
  const float* cb1  = (const float*)d_in[19];
  const float* cw2  = (const float*)d_in[20];
  const float* cb2  = (const float*)d_in[21];
  const float* rw1  = (const float*)d_in[22];
  const float* rb1  = (const float*)d_in[23];
  const float* rw2  = (const float*)d_in[24];
  const float* rb2  = (const float*)d_in[25];

  // workspace (~38.5 MB), no aliasing needed anymore
  uint*  h1u = (uint*)d_ws;               // N*32 uints (bf16x2) = 12.8MB
  uint*  h2u = h1u + NN * 32;             // N*16 uints = 6.4MB
  float* as1 = (float*)(h2u + NN * 16);   // N*4
  float* ad1 = as1 + NN * NHEADS;         // N*4
  float* as2 = ad1 + NN * NHEADS;         // N
  float* ad2 = as2 + NN;                  // N
  int* rowp  = (int*)(ad2 + NN);          // N+1
  int* srcs  = rowp + NN + 1;             // ETOT
  int* bcur  = srcs + ETOT;               // 256
  int* bins  = bcur + 256;                // NBUCK*CAP = 2.0M ints (8MB)

  float* out        = (float*)d_out;
  float* out_emb    = out;                   // N*32
  float* out_roles  = out + NN * OUTD;       // N*3
  float* out_energy = out + NN * (OUTD + 3); // N*1

  hipMemsetAsync(bcur, 0, NBUCK * sizeof(int), stream);
  k_bin<<<(ETOT + EPB - 1) / EPB, 256, 0, stream>>>(ei, bcur, bins);
  k_csr<<<NBUCK, 256, 0, stream>>>(bcur, bins, rowp, srcs);
  k_lin1<<<NN / 8, 256, 0, stream>>>(x, W1, as1w, ad1w, h1u, as1, ad1);
  k_agg1f<<<NN / 4, 256, 0, stream>>>(rowp, srcs, h1u, as1, ad1, b1,
                                      bn1g, bn1b, bn1m, bn1v,
                                      W2, as2w, ad2w, h2u, as2, ad2);
  k_agg2f<<<NN / 4, 256, 0, stream>>>(rowp, srcs, h2u, as2, ad2, b2v,
                                      bn2g, bn2b, bn2m, bn2v,
                                      cw1, cb1, cw2, cb2, rw1, rb1, rw2, rb2,
                                      out_emb, out_roles, out_energy);
}

// Round 8
// 376.086 us; speedup vs baseline: 1.0032x; 1.0032x over previous
//
#include <hip/hip_runtime.h>
#include <hip/hip_bf16.h>

#define NN 100000
#define EE 1600000
#define ETOT (EE + NN)          // 1,700,000 edges incl. self-loops
#define IND 32
#define HIDD 64
#define NHEADS 4
#define OUTD 32
#define HID2D 32

#define BSH 9                   // 512 nodes per bucket
#define NBUCK 196               // ceil(NN / 512)
#define CAP 10240               // max edges per bucket (mean ~8675)
#define EPB 8192                // edges per k_bin block

typedef unsigned int uint;

__device__ __forceinline__ uint pack2(float a, float b) {
  uint lo = (uint)__bfloat16_as_ushort(__float2bfloat16(a));
  uint hi = (uint)__bfloat16_as_ushort(__float2bfloat16(b));
  return (hi << 16) | lo;
}
__device__ __forceinline__ float lo2f(uint w) { return __uint_as_float(w << 16); }
__device__ __forceinline__ float hi2f(uint w) { return __uint_as_float(w & 0xFFFF0000u); }

// ---------- linear 1: h1(bf16) = x @ W1 ; as1/ad1 f32 attention dots ----------
__global__ __launch_bounds__(256) void k_lin1(
    const float* __restrict__ x, const float* __restrict__ W1,
    const float* __restrict__ atsrc, const float* __restrict__ atdst,
    uint* __restrict__ h1u, float* __restrict__ as1, float* __restrict__ ad1) {
  __shared__ float Ws[IND * HIDD];
  __shared__ float xs[8 * IND];
  __shared__ float atS[HIDD], atD[HIDD];
  int t = threadIdx.x;
  for (int i = t; i < IND * HIDD; i += 256) Ws[i] = W1[i];
  if (t < HIDD) { atS[t] = atsrc[t]; atD[t] = atdst[t]; }
  xs[t] = x[blockIdx.x * 256 + t];
  __syncthreads();
  int nl = t >> 5, tl = t & 31;
  int node = blockIdx.x * 8 + nl;
  int j0 = 2 * tl, j1 = j0 + 1;
  float a0 = 0.f, a1 = 0.f;
#pragma unroll
  for (int k = 0; k < IND; k++) {
    float xv = xs[nl * IND + k];
    a0 += xv * Ws[k * HIDD + j0];
    a1 += xv * Ws[k * HIDD + j1];
  }
  h1u[node * 32 + tl] = pack2(a0, a1);
  float ps = a0 * atS[j0] + a1 * atS[j1];
  float pd = a0 * atD[j0] + a1 * atD[j1];
#pragma unroll
  for (int off = 4; off >= 1; off >>= 1) {
    ps += __shfl_down(ps, off, 8);
    pd += __shfl_down(pd, off, 8);
  }
  if ((tl & 7) == 0) {
    as1[node * NHEADS + (tl >> 3)] = ps;
    ad1[node * NHEADS + (tl >> 3)] = pd;
  }
}

// ---------- pass 1: bucket edges by dst>>9 (count, reserve, re-read & scatter) ----------
__global__ __launch_bounds__(256) void k_bin(const int* __restrict__ ei,
                                             int* __restrict__ bcur,
                                             int* __restrict__ bins) {
  __shared__ int cnt[NBUCK];
  int t = threadIdx.x;
  for (int i = t; i < NBUCK; i += 256) cnt[i] = 0;
  __syncthreads();
  int base = blockIdx.x * EPB;
  int lim = base + EPB; if (lim > ETOT) lim = ETOT;
  for (int i = base + t; i < lim; i += 256) {
    int d = (i < EE) ? ei[EE + i] : (i - EE);
    atomicAdd(&cnt[d >> BSH], 1);
  }
  __syncthreads();
  // reserve this block's range in each bucket; cnt becomes the running cursor
  for (int i = t; i < NBUCK; i += 256) cnt[i] = atomicAdd(&bcur[i], cnt[i]);
  __syncthreads();
  for (int i = base + t; i < lim; i += 256) {
    int s, d;
    if (i < EE) { s = ei[i]; d = ei[EE + i]; } else { s = i - EE; d = s; }
    int bk = d >> BSH;
    int pos = atomicAdd(&cnt[bk], 1);
    bins[bk * CAP + pos] = (s << BSH) | (d & ((1 << BSH) - 1));
  }
}

// ---------- pass 2: per-bucket local CSR, with inline 196-scan ----------
__global__ __launch_bounds__(256) void k_csr(const int* __restrict__ bcur,
                                             const int* __restrict__ bins,
                                             int* __restrict__ rowp,
                                             int* __restrict__ srcs) {
  __shared__ int lrec[CAP];
  __shared__ int ldeg[512], sA[512], sB[512];
  int b = blockIdx.x, t = threadIdx.x;
  // inline exclusive scan of the 196 bucket counts (redundant per block, cheap)
  {
    int v = (t < NBUCK) ? bcur[t] : 0;
    sA[t] = v;
    if (t >= 256) sA[t] = 0;
  }
  __syncthreads();
  int* in = sA; int* out = sB;
  for (int off = 1; off < 256; off <<= 1) {
    out[t] = in[t] + ((t >= off && t < 256) ? in[t - off] : 0);
    if (t >= 256) out[t] = 0;
    __syncthreads();
    int* tmp = in; in = out; out = tmp;
  }
  int gb = (b == 0) ? 0 : in[b - 1];
  if (b == 0 && t == 0) rowp[NN] = ETOT;
  __syncthreads();
  int count = bcur[b]; if (count > CAP) count = CAP;
  for (int i = t; i < 512; i += 256) ldeg[i] = 0;
  __syncthreads();
  for (int i = t; i < count; i += 256) {
    int r = bins[b * CAP + i];
    lrec[i] = r;
    atomicAdd(&ldeg[r & 511], 1);
  }
  __syncthreads();
  for (int i = t; i < 512; i += 256) sA[i] = ldeg[i];
  __syncthreads();
  in = sA; out = sB;
  for (int off = 1; off < 512; off <<= 1) {
    for (int i = t; i < 512; i += 256)
      out[i] = in[i] + ((i >= off) ? in[i - off] : 0);
    __syncthreads();
    int* tmp = in; in = out; out = tmp;
  }
  int nb = b << BSH;
  for (int i = t; i < 512; i += 256) {
    int ex = in[i] - ldeg[i];          // exclusive scan
    if (nb + i < NN) rowp[nb + i] = gb + ex;
    ldeg[i] = ex;                      // reuse as scatter cursor
  }
  __syncthreads();
  for (int i = t; i < count; i += 256) {
    int r = lrec[i];
    int pos = atomicAdd(&ldeg[r & 511], 1);
    srcs[gb + pos] = r >> BSH;
  }
}

// ---------- GAT1 agg + BN1 + ReLU + barrier-free fused lin2 ----------
// wave per node; 8 edge slots x 8 lanes; lane reads uint4 = 8 bf16 features.
// No LDS, no __syncthreads: xor-butterfly replicates the row to all lanes;
// epilogue matvec reads W2 from global (8KB, L1-resident).
__global__ __launch_bounds__(256) void k_agg1e(
    const int* __restrict__ rowp, const int* __restrict__ srcs,
    const uint* __restrict__ h1u, const float* __restrict__ as1,
    const float* __restrict__ ad1, const float* __restrict__ b1,
    const float* __restrict__ g, const float* __restrict__ bb,
    const float* __restrict__ m, const float* __restrict__ v,
    const float* __restrict__ W2, const float* __restrict__ atsrc2,
    const float* __restrict__ atdst2,
    uint* __restrict__ h2u, float* __restrict__ as2, float* __restrict__ ad2) {
  int t = threadIdx.x;
  int wid = t >> 6, lane = t & 63;
  int node = blockIdx.x * 4 + wid;
  int slot = lane >> 3;      // edge slot (8)
  int fl = lane & 7;         // feature group: feats fl*8..fl*8+7
  int hd = fl >> 1;
  int start = rowp[node], end = rowp[node + 1];
  int lastp = end - 1;       // deg >= 1 always (self-loop)
  float adv = ad1[node * NHEADS + hd];
  const uint4* h14 = (const uint4*)h1u;
  float acc[8] = {0.f, 0.f, 0.f, 0.f, 0.f, 0.f, 0.f, 0.f};
  float l = 0.f;
  int p = start + slot;
  int pc = p < lastp ? p : lastp;
  int s0 = srcs[pc];
  uint4 w = h14[s0 * 8 + fl];
  float as = as1[s0 * NHEADS + hd];
  int p1 = p + 8;
  int pc1 = p1 < lastp ? p1 : lastp;
  int s1 = srcs[pc1];
  while (p < end) {
    uint4 wn = h14[s1 * 8 + fl];
    float asn = as1[s1 * NHEADS + hd];
    int p2 = p1 + 8;
    int pc2 = p2 < lastp ? p2 : lastp;
    int s2 = srcs[pc2];
    float e = as + adv;
    e = fmaxf(e, 0.2f * e);
    float ex = __expf(e);
    l += ex;
    acc[0] += ex * lo2f(w.x); acc[1] += ex * hi2f(w.x);
    acc[2] += ex * lo2f(w.y); acc[3] += ex * hi2f(w.y);
    acc[4] += ex * lo2f(w.z); acc[5] += ex * hi2f(w.z);
    acc[6] += ex * lo2f(w.w); acc[7] += ex * hi2f(w.w);
    w = wn; as = asn; s1 = s2; p = p1; p1 = p2;
  }
#pragma unroll
  for (int off = 8; off <= 32; off <<= 1) {
#pragma unroll
    for (int i = 0; i < 8; i++) acc[i] += __shfl_xor(acc[i], off, 64);
    l += __shfl_xor(l, off, 64);
  }
  // all 64 lanes now hold the full sums for their fl group: BN+ReLU in-register
  float li = 1.f / (l + 1e-16f);
  int fb = fl * 8;
  float o[8];
#pragma unroll
  for (int i = 0; i < 8; i++) {
    int j = fb + i;
    float ov = acc[i] * li + b1[j];
    ov = (ov - m[j]) * rsqrtf(v[j] + 1e-5f) * g[j] + bb[j];
    o[i] = fmaxf(ov, 0.f);
  }
  // fused lin2: h2[j] = row @ W2[:,j]; row[k] via width-8 shuffle broadcast
  int j = lane & 31, half = lane >> 5;
  float hv = 0.f;
#pragma unroll
  for (int k = 0; k < HIDD; k++) {
    float rk = __shfl(o[k & 7], k >> 3, 8);
    hv += rk * W2[k * OUTD + j];
  }
  float av = half ? atdst2[j] : atsrc2[j];
  float pr = hv * av;
#pragma unroll
  for (int off = 1; off <= 16; off <<= 1) pr += __shfl_xor(pr, off, 64);
  if (lane == 0) as2[node] = pr;
  if (lane == 32) ad2[node] = pr;
  float hn = __shfl_down(hv, 1, 64);
  if (half == 0 && (j & 1) == 0) h2u[node * 16 + (j >> 1)] = pack2(hv, hn);
}

// ---------- GAT2 agg + BN2 + ReLU + emb + barrier-free fused MLP heads ----------
// wave per node; 8 edge slots x 8 lanes; lane reads uint2 = 4 bf16 features.
__global__ __launch_bounds__(256) void k_agg2e(
    const int* __restrict__ rowp, const int* __restrict__ srcs,
    const uint* __restrict__ h2u, const float* __restrict__ as2,
    const float* __restrict__ ad2, const float* __restrict__ b2v,
    const float* __restrict__ g, const float* __restrict__ bb,
    const float* __restrict__ m, const float* __restrict__ v,
    const float* __restrict__ cw1, const float* __restrict__ cb1,
    const float* __restrict__ cw2, const float* __restrict__ cb2,
    const float* __restrict__ rw1, const float* __restrict__ rb1,
    const float* __restrict__ rw2, const float* __restrict__ rb2,
    float* __restrict__ out_emb, float* __restrict__ out_roles,
    float* __restrict__ out_energy) {
  int t = threadIdx.x;
  int wid = t >> 6, lane = t & 63;
  int node = blockIdx.x * 4 + wid;
  int slot = lane >> 3;
  int fl = lane & 7;         // feats fl*4..fl*4+3
  int start = rowp[node], end = rowp[node + 1];
  int lastp = end - 1;
  float adv = ad2[node];
  const uint2* h22 = (const uint2*)h2u;
  float acc[4] = {0.f, 0.f, 0.f, 0.f};
  float l = 0.f;
  int p = start + slot;
  int pc = p < lastp ? p : lastp;
  int s0 = srcs[pc];
  uint2 w = h22[s0 * 8 + fl];
  float as = as2[s0];
  int p1 = p + 8;
  int pc1 = p1 < lastp ? p1 : lastp;
  int s1 = srcs[pc1];
  while (p < end) {
    uint2 wn = h22[s1 * 8 + fl];
    float asn = as2[s1];
    int p2 = p1 + 8;
    int pc2 = p2 < lastp ? p2 : lastp;
    int s2 = srcs[pc2];
    float e = as + adv;
    e = fmaxf(e, 0.2f * e);
    float ex = __expf(e);
    l += ex;
    acc[0] += ex * lo2f(w.x); acc[1] += ex * hi2f(w.x);
    acc[2] += ex * lo2f(w.y); acc[3] += ex * hi2f(w.y);
    w = wn; as = asn; s1 = s2; p = p1; p1 = p2;
  }
#pragma unroll
  for (int off = 8; off <= 32; off <<= 1) {
#pragma unroll
    for (int i = 0; i < 4; i++) acc[i] += __shfl_xor(acc[i], off, 64);
    l += __shfl_xor(l, off, 64);
  }
  // BN+ReLU in all lanes (sums replicated); slot-0 lanes store emb
  float li = 1.f / (l + 1e-16f);
  int fb = fl * 4;
  float o[4];
#pragma unroll
  for (int i = 0; i < 4; i++) {
    int j2 = fb + i;
    float ov = acc[i] * li + b2v[j2];
    ov = (ov - m[j2]) * rsqrtf(v[j2] + 1e-5f) * g[j2] + bb[j2];
    o[i] = fmaxf(ov, 0.f);
  }
  if (slot == 0)
    *(float4*)(out_emb + node * OUTD + fb) = make_float4(o[0], o[1], o[2], o[3]);
  // fused heads: lanes 0-31 classifier hidden j, lanes 32-63 regressor hidden j
  int j = lane & 31, half = lane >> 5;
  const float* w1p = half ? rw1 : cw1;
  float a2 = half ? rb1[j] : cb1[j];
#pragma unroll
  for (int k = 0; k < OUTD; k++) {
    float rk = __shfl(o[k & 3], k >> 2, 8);
    a2 += rk * w1p[k * HID2D + j];
  }
  a2 = fmaxf(a2, 0.f);
  float p0, p1v, p2v;
  if (half == 0) {
    p0 = a2 * cw2[j * 3 + 0];
    p1v = a2 * cw2[j * 3 + 1];
    p2v = a2 * cw2[j * 3 + 2];
  } else {
    p0 = a2 * rw2[j];
    p1v = 0.f; p2v = 0.f;
  }
#pragma unroll
  for (int off = 1; off <= 16; off <<= 1) {
    p0 += __shfl_xor(p0, off, 64);
    p1v += __shfl_xor(p1v, off, 64);
    p2v += __shfl_xor(p2v, off, 64);
  }
  if (lane == 0) {
    out_roles[node * 3 + 0] = p0 + cb2[0];
    out_roles[node * 3 + 1] = p1v + cb2[1];
    out_roles[node * 3 + 2] = p2v + cb2[2];
  }
  if (lane == 32) out_energy[node] = p0 + rb2[0];
}

extern "C" void kernel_launch(void* const* d_in, const int* in_sizes, int n_in,
                              void* d_out, int out_size, void* d_ws, size_t ws_size,
                              hipStream_t stream) {
  const float* x    = (const float*)d_in[0];
  const int*   ei   = (const int*)d_in[1];
  const float* W1   = (const float*)d_in[2];
  const float* as1w = (const float*)d_in[3];
  const float* ad1w = (const float*)d_in[4];
  const float* b1   = (const float*)d_in[5];
  const float* W2   = (const float*)d_in[6];
  const float* as2w = (const float*)d_in[7];
  const float* ad2w = (const float*)d_in[8];
  const float* b2v  = (const float*)d_in[9];
  const float* bn1g = (const float*)d_in[10];
  const float* bn1b = (const float*)d_in[11];
  const float* bn1m = (const float*)d_in[12];
  const float* bn1v = (const float*)d_in[13];
  const float* bn2g = (const float*)d_in[14];
  const float* bn2b = (const float*)d_in[15];
  const float* bn2m = (const float*)d_in[16];
  const float* bn2v = (const float*)d_in[17];
  const float* cw1  = (const float*)d_in[18];
  const float* cb1  = (const float*)d_in[19];
  const float* cw2  = (const float*)d_in[20];
  const float* cb2  = (const float*)d_in[21];
  const float* rw1  = (const float*)d_in[22];
  const float* rb1  = (const float*)d_in[23];
  const float* rw2  = (const float*)d_in[24];
  const float* rb2  = (const float*)d_in[25];

  // workspace (~38.9 MB)
  uint*  h1u = (uint*)d_ws;               // N*32 uints (bf16x2) = 12.8MB
  uint*  h2u = h1u + NN * 32;             // N*16 uints = 6.4MB
  float* as1 = (float*)(h2u + NN * 16);   // N*4
  float* ad1 = as1 + NN * NHEADS;         // N*4
  float* as2 = ad1 + NN * NHEADS;         // N
  float* ad2 = as2 + NN;                  // N
  int* rowp  = (int*)(ad2 + NN);          // N+1
  int* srcs  = rowp + NN + 1;             // ETOT
  int* bcur  = srcs + ETOT;               // 256
  int* bins  = bcur + 256;                // NBUCK*CAP = 2.0M ints (8MB)

  float* out        = (float*)d_out;
  float* out_emb    = out;                   // N*32
  float* out_roles  = out + NN * OUTD;       // N*3
  float* out_energy = out + NN * (OUTD + 3); // N*1

  hipMemsetAsync(bcur, 0, NBUCK * sizeof(int), stream);
  k_bin<<<(ETOT + EPB - 1) / EPB, 256, 0, stream>>>(ei, bcur, bins);
  k_csr<<<NBUCK, 256, 0, stream>>>(bcur, bins, rowp, srcs);
  k_lin1<<<NN / 8, 256, 0, stream>>>(x, W1, as1w, ad1w, h1u, as1, ad1);
  k_agg1e<<<NN / 4, 256, 0, stream>>>(rowp, srcs, h1u, as1, ad1, b1,
                                      bn1g, bn1b, bn1m, bn1v,
                                      W2, as2w, ad2w, h2u, as2, ad2);
  k_agg2e<<<NN / 4, 256, 0, stream>>>(rowp, srcs, h2u, as2, ad2, b2v,
                                      bn2g, bn2b, bn2m, bn2v,
                                      cw1, cb1, cw2, cb2, rw1, rb1, rw2, rb2,
                                      out_emb, out_roles, out_energy);
}

// Round 10
// 346.548 us; speedup vs baseline: 1.0887x; 1.0852x over previous
//
#include <hip/hip_runtime.h>
#include <hip/hip_bf16.h>

#define NN 100000
#define EE 1600000
#define ETOT (EE + NN)          // 1,700,000 edges incl. self-loops
#define IND 32
#define HIDD 64
#define NHEADS 4
#define OUTD 32
#define HID2D 32

#define BSH 9                   // 512 nodes per bucket
#define NBUCK 196               // ceil(NN / 512)
#define CAP 10240               // max edges per bucket (mean ~8675)
#define EPB 2048                // edges per k_bin block

typedef unsigned int uint;

__device__ __forceinline__ uint pack2(float a, float b) {
  uint lo = (uint)__bfloat16_as_ushort(__float2bfloat16(a));
  uint hi = (uint)__bfloat16_as_ushort(__float2bfloat16(b));
  return (hi << 16) | lo;
}
__device__ __forceinline__ float lo2f(uint w) { return __uint_as_float(w << 16); }
__device__ __forceinline__ float hi2f(uint w) { return __uint_as_float(w & 0xFFFF0000u); }

// ---------- linear 1: h1(bf16) = x @ W1 ; as1/ad1 f32 attention dots ----------
__global__ __launch_bounds__(256) void k_lin1(
    const float* __restrict__ x, const float* __restrict__ W1,
    const float* __restrict__ atsrc, const float* __restrict__ atdst,
    uint* __restrict__ h1u, float* __restrict__ as1, float* __restrict__ ad1) {
  __shared__ float Ws[IND * HIDD];
  __shared__ float xs[8 * IND];
  __shared__ float atS[HIDD], atD[HIDD];
  int t = threadIdx.x;
  for (int i = t; i < IND * HIDD; i += 256) Ws[i] = W1[i];
  if (t < HIDD) { atS[t] = atsrc[t]; atD[t] = atdst[t]; }
  xs[t] = x[blockIdx.x * 256 + t];
  __syncthreads();
  int nl = t >> 5, tl = t & 31;
  int node = blockIdx.x * 8 + nl;
  int j0 = 2 * tl, j1 = j0 + 1;
  float a0 = 0.f, a1 = 0.f;
#pragma unroll
  for (int k = 0; k < IND; k++) {
    float xv = xs[nl * IND + k];
    a0 += xv * Ws[k * HIDD + j0];
    a1 += xv * Ws[k * HIDD + j1];
  }
  h1u[node * 32 + tl] = pack2(a0, a1);
  float ps = a0 * atS[j0] + a1 * atS[j1];
  float pd = a0 * atD[j0] + a1 * atD[j1];
#pragma unroll
  for (int off = 4; off >= 1; off >>= 1) {
    ps += __shfl_down(ps, off, 8);
    pd += __shfl_down(pd, off, 8);
  }
  if ((tl & 7) == 0) {
    as1[node * NHEADS + (tl >> 3)] = ps;
    ad1[node * NHEADS + (tl >> 3)] = pd;
  }
}

// ---------- linear 2: h2(bf16) = hbn(f32) @ W2 ; as2/ad2 ----------
__global__ __launch_bounds__(256) void k_lin2(
    const float* __restrict__ hbn, const float* __restrict__ W2,
    const float* __restrict__ atsrc, const float* __restrict__ atdst,
    uint* __restrict__ h2u, float* __restrict__ as2, float* __restrict__ ad2) {
  __shared__ float Ws[HIDD * OUTD];
  __shared__ float xs[16 * HIDD];
  __shared__ float atS[OUTD], atD[OUTD];
  int t = threadIdx.x;
  for (int i = t; i < HIDD * OUTD; i += 256) Ws[i] = W2[i];
  if (t < OUTD) { atS[t] = atsrc[t]; atD[t] = atdst[t]; }
  for (int i = t; i < 16 * HIDD; i += 256) xs[i] = hbn[blockIdx.x * 16 * HIDD + i];
  __syncthreads();
  int nl = t >> 4, tl = t & 15;
  int node = blockIdx.x * 16 + nl;
  int j0 = 2 * tl, j1 = j0 + 1;
  float a0 = 0.f, a1 = 0.f;
#pragma unroll
  for (int k = 0; k < HIDD; k++) {
    float xv = xs[nl * HIDD + k];
    a0 += xv * Ws[k * OUTD + j0];
    a1 += xv * Ws[k * OUTD + j1];
  }
  h2u[node * 16 + tl] = pack2(a0, a1);
  float ps = a0 * atS[j0] + a1 * atS[j1];
  float pd = a0 * atD[j0] + a1 * atD[j1];
#pragma unroll
  for (int off = 8; off >= 1; off >>= 1) {
    ps += __shfl_down(ps, off, 16);
    pd += __shfl_down(pd, off, 16);
  }
  if (tl == 0) { as2[node] = ps; ad2[node] = pd; }
}

// ---------- pass 1: bucket edges by dst>>9; record = (src<<9)|(dst&511) ----------
__global__ __launch_bounds__(256) void k_bin(const int* __restrict__ ei,
                                             int* __restrict__ bcur,
                                             int* __restrict__ bins) {
  __shared__ int cnt[NBUCK];
  int t = threadIdx.x;
  for (int i = t; i < NBUCK; i += 256) cnt[i] = 0;
  __syncthreads();
  int base = blockIdx.x * EPB;
  int recs[8], bks[8];
#pragma unroll
  for (int k = 0; k < 8; k++) {
    int i = base + k * 256 + t;
    recs[k] = -1; bks[k] = 0;
    if (i < ETOT) {
      int s, d;
      if (i < EE) { s = ei[i]; d = ei[EE + i]; } else { s = i - EE; d = s; }
      recs[k] = (s << BSH) | (d & ((1 << BSH) - 1));
      bks[k] = d >> BSH;
      atomicAdd(&cnt[bks[k]], 1);
    }
  }
  __syncthreads();
  for (int i = t; i < NBUCK; i += 256) cnt[i] = atomicAdd(&bcur[i], cnt[i]);
  __syncthreads();
#pragma unroll
  for (int k = 0; k < 8; k++) {
    if (recs[k] >= 0) {
      int pos = atomicAdd(&cnt[bks[k]], 1);
      bins[bks[k] * CAP + pos] = recs[k];
    }
  }
}

// ---------- pass 2: per-bucket local CSR, with inline 196-scan ----------
__global__ __launch_bounds__(256) void k_csr(const int* __restrict__ bcur,
                                             const int* __restrict__ bins,
                                             int* __restrict__ rowp,
                                             int* __restrict__ srcs) {
  __shared__ int lrec[CAP];
  __shared__ int ldeg[512], sA[512], sB[512];
  int b = blockIdx.x, t = threadIdx.x;
  // inline exclusive scan of the 196 bucket counts (redundant per block, cheap)
  sA[t] = (t < NBUCK) ? bcur[t] : 0;
  __syncthreads();
  int* in = sA; int* out = sB;
  for (int off = 1; off < 256; off <<= 1) {
    out[t] = in[t] + ((t >= off) ? in[t - off] : 0);
    __syncthreads();
    int* tmp = in; in = out; out = tmp;
  }
  int gb = (b == 0) ? 0 : in[b - 1];
  if (b == 0 && t == 0) rowp[NN] = ETOT;
  __syncthreads();
  int count = bcur[b]; if (count > CAP) count = CAP;
  for (int i = t; i < 512; i += 256) ldeg[i] = 0;
  __syncthreads();
  for (int i = t; i < count; i += 256) {
    int r = bins[b * CAP + i];
    lrec[i] = r;
    atomicAdd(&ldeg[r & 511], 1);
  }
  __syncthreads();
  for (int i = t; i < 512; i += 256) sA[i] = ldeg[i];
  __syncthreads();
  in = sA; out = sB;
  for (int off = 1; off < 512; off <<= 1) {
    for (int i = t; i < 512; i += 256)
      out[i] = in[i] + ((i >= off) ? in[i - off] : 0);
    __syncthreads();
    int* tmp = in; in = out; out = tmp;
  }
  int nb = b << BSH;
  for (int i = t; i < 512; i += 256) {
    int ex = in[i] - ldeg[i];          // exclusive scan
    if (nb + i < NN) rowp[nb + i] = gb + ex;
    ldeg[i] = ex;                      // reuse as scatter cursor
  }
  __syncthreads();
  for (int i = t; i < count; i += 256) {
    int r = lrec[i];
    int pos = atomicAdd(&ldeg[r & 511], 1);
    srcs[gb + pos] = r >> BSH;
  }
}

// ---------- GAT1 aggregation + bias + BN1 + ReLU, DUAL-node waves ----------
// wave per 2 nodes; 8 edge slots x 8 lanes; lane reads uint4 = 8 bf16 feats.
// Two independent gather pipelines (A,B) double the lines in flight.
__global__ __launch_bounds__(256) void k_agg1(
    const int* __restrict__ rowp, const int* __restrict__ srcs,
    const uint* __restrict__ h1u, const float* __restrict__ as1,
    const float* __restrict__ ad1, const float* __restrict__ b1,
    const float* __restrict__ g, const float* __restrict__ bb,
    const float* __restrict__ m, const float* __restrict__ v,
    float* __restrict__ hbn) {
  int t = threadIdx.x;
  int wid = t >> 6, lane = t & 63;
  int nA = blockIdx.x * 8 + wid * 2;
  int nB = nA + 1;
  int slot = lane >> 3;
  int fl = lane & 7;
  int hd = fl >> 1;
  int stA = rowp[nA], eA = rowp[nA + 1], eB = rowp[nB + 1];
  int stB = eA;
  int lpA = eA - 1, lpB = eB - 1;      // deg >= 1 (self-loop)
  float advA = ad1[nA * NHEADS + hd];
  float advB = ad1[nB * NHEADS + hd];
  const uint4* h14 = (const uint4*)h1u;
  float accA[8] = {0,0,0,0,0,0,0,0}, accB[8] = {0,0,0,0,0,0,0,0};
  float lA = 0.f, lB = 0.f;
  int pA = stA + slot, pB = stB + slot;
  int sA0 = srcs[pA < lpA ? pA : lpA];
  int sB0 = srcs[pB < lpB ? pB : lpB];
  uint4 wA = h14[sA0 * 8 + fl];
  uint4 wB = h14[sB0 * 8 + fl];
  float asA = as1[sA0 * NHEADS + hd];
  float asB = as1[sB0 * NHEADS + hd];
  int p1A = pA + 8, p1B = pB + 8;
  int sA1 = srcs[p1A < lpA ? p1A : lpA];
  int sB1 = srcs[p1B < lpB ? p1B : lpB];
  while (pA < eA || pB < eB) {
    uint4 wnA = h14[sA1 * 8 + fl];
    uint4 wnB = h14[sB1 * 8 + fl];
    float anA = as1[sA1 * NHEADS + hd];
    float anB = as1[sB1 * NHEADS + hd];
    int p2A = p1A + 8, p2B = p1B + 8;
    int sA2 = srcs[p2A < lpA ? p2A : lpA];
    int sB2 = srcs[p2B < lpB ? p2B : lpB];
    if (pA < eA) {
      float e = asA + advA;
      e = fmaxf(e, 0.2f * e);
      float ex = __expf(e);
      lA += ex;
      accA[0] += ex * lo2f(wA.x); accA[1] += ex * hi2f(wA.x);
      accA[2] += ex * lo2f(wA.y); accA[3] += ex * hi2f(wA.y);
      accA[4] += ex * lo2f(wA.z); accA[5] += ex * hi2f(wA.z);
      accA[6] += ex * lo2f(wA.w); accA[7] += ex * hi2f(wA.w);
    }
    if (pB < eB) {
      float e = asB + advB;
      e = fmaxf(e, 0.2f * e);
      float ex = __expf(e);
      lB += ex;
      accB[0] += ex * lo2f(wB.x); accB[1] += ex * hi2f(wB.x);
      accB[2] += ex * lo2f(wB.y); accB[3] += ex * hi2f(wB.y);
      accB[4] += ex * lo2f(wB.z); accB[5] += ex * hi2f(wB.z);
      accB[6] += ex * lo2f(wB.w); accB[7] += ex * hi2f(wB.w);
    }
    wA = wnA; wB = wnB; asA = anA; asB = anB;
    sA1 = sA2; sB1 = sB2;
    pA = p1A; pB = p1B; p1A = p2A; p1B = p2B;
  }
#pragma unroll
  for (int off = 8; off <= 32; off <<= 1) {
#pragma unroll
    for (int i = 0; i < 8; i++) {
      accA[i] += __shfl_xor(accA[i], off, 64);
      accB[i] += __shfl_xor(accB[i], off, 64);
    }
    lA += __shfl_xor(lA, off, 64);
    lB += __shfl_xor(lB, off, 64);
  }
  if (slot < 2) {
    int node = slot == 0 ? nA : nB;
    float lsum = slot == 0 ? lA : lB;
    float li = 1.f / (lsum + 1e-16f);
    int fb = fl * 8;
    float o[8];
#pragma unroll
    for (int i = 0; i < 8; i++) {
      int j = fb + i;
      float av = slot == 0 ? accA[i] : accB[i];
      float ov = av * li + b1[j];
      ov = (ov - m[j]) * rsqrtf(v[j] + 1e-5f) * g[j] + bb[j];
      o[i] = fmaxf(ov, 0.f);
    }
    float4* dst = (float4*)(hbn + node * HIDD + fb);
    dst[0] = make_float4(o[0], o[1], o[2], o[3]);
    dst[1] = make_float4(o[4], o[5], o[6], o[7]);
  }
}

// ---------- GAT2 aggregation + bias + BN2 + ReLU (round-6 single-node) ----------
// wave per node; 8 edge slots x 8 lanes; lane reads uint2 = 4 bf16 features.
__global__ __launch_bounds__(256) void k_agg2(
    const int* __restrict__ rowp, const int* __restrict__ srcs,
    const uint* __restrict__ h2u, const float* __restrict__ as2,
    const float* __restrict__ ad2, const float* __restrict__ b2v,
    const float* __restrict__ g, const float* __restrict__ bb,
    const float* __restrict__ m, const float* __restrict__ v,
    float* __restrict__ out_emb) {
  int t = threadIdx.x;
  int wid = t >> 6, lane = t & 63;
  int node = blockIdx.x * 4 + wid;
  int slot = lane >> 3;
  int fl = lane & 7;         // feats fl*4..fl*4+3
  int start = rowp[node], end = rowp[node + 1];
  int lastp = end - 1;
  float adv = ad2[node];
  const uint2* h22 = (const uint2*)h2u;
  float acc[4] = {0.f, 0.f, 0.f, 0.f};
  float l = 0.f;
  int p = start + slot;
  int pc = p < lastp ? p : lastp;
  int s0 = srcs[pc];
  uint2 w = h22[s0 * 8 + fl];
  float as = as2[s0];
  int p1 = p + 8;
  int pc1 = p1 < lastp ? p1 : lastp;
  int s1 = srcs[pc1];
  while (p < end) {
    uint2 wn = h22[s1 * 8 + fl];
    float asn = as2[s1];
    int p2 = p1 + 8;
    int pc2 = p2 < lastp ? p2 : lastp;
    int s2 = srcs[pc2];
    float e = as + adv;
    e = fmaxf(e, 0.2f * e);
    float ex = __expf(e);
    l += ex;
    acc[0] += ex * lo2f(w.x); acc[1] += ex * hi2f(w.x);
    acc[2] += ex * lo2f(w.y); acc[3] += ex * hi2f(w.y);
    w = wn; as = asn; s1 = s2; p = p1; p1 = p2;
  }
#pragma unroll
  for (int off = 8; off <= 32; off <<= 1) {
#pragma unroll
    for (int i = 0; i < 4; i++) acc[i] += __shfl_xor(acc[i], off, 64);
    l += __shfl_xor(l, off, 64);
  }
  if (slot == 0) {
    float li = 1.f / (l + 1e-16f);
    int fb = fl * 4;
    float o[4];
#pragma unroll
    for (int i = 0; i < 4; i++) {
      int j = fb + i;
      float ov = acc[i] * li + b2v[j];
      ov = (ov - m[j]) * rsqrtf(v[j] + 1e-5f) * g[j] + bb[j];
      o[i] = fmaxf(ov, 0.f);
    }
    *(float4*)(out_emb + node * OUTD + fb) = make_float4(o[0], o[1], o[2], o[3]);
  }
}

// ---------- classifier + regressor heads (thread per node) ----------
__global__ __launch_bounds__(256) void k_mlp(
    const float* __restrict__ embf,
    const float* __restrict__ cw1, const float* __restrict__ cb1,
    const float* __restrict__ cw2, const float* __restrict__ cb2,
    const float* __restrict__ rw1, const float* __restrict__ rb1,
    const float* __restrict__ rw2, const float* __restrict__ rb2,
    float* __restrict__ out_roles, float* __restrict__ out_energy) {
  __shared__ float C1[OUTD * HID2D], R1[OUTD * HID2D];
  __shared__ float C2[HID2D * 3], CB1[HID2D], RB1[HID2D], R2[HID2D];
  __shared__ float CB2v[3], RB2v;
  int t = threadIdx.x;
  for (int i = t; i < OUTD * HID2D; i += 256) { C1[i] = cw1[i]; R1[i] = rw1[i]; }
  if (t < HID2D) { CB1[t] = cb1[t]; RB1[t] = rb1[t]; R2[t] = rw2[t]; }
  if (t < HID2D * 3) C2[t] = cw2[t];
  if (t < 3) CB2v[t] = cb2[t];
  if (t == 0) RB2v = rb2[0];
  __syncthreads();
  int node = blockIdx.x * 256 + t;
  if (node >= NN) return;
  float e[OUTD];
#pragma unroll
  for (int k = 0; k < OUTD; k++) e[k] = embf[node * OUTD + k];
  float r0 = CB2v[0], r1 = CB2v[1], r2 = CB2v[2], en = RB2v;
  for (int j = 0; j < HID2D; j++) {
    float hc = CB1[j], hr = RB1[j];
#pragma unroll
    for (int k = 0; k < OUTD; k++) {
      hc += e[k] * C1[k * HID2D + j];
      hr += e[k] * R1[k * HID2D + j];
    }
    hc = fmaxf(hc, 0.f);
    hr = fmaxf(hr, 0.f);
    r0 += hc * C2[j * 3 + 0];
    r1 += hc * C2[j * 3 + 1];
    r2 += hc * C2[j * 3 + 2];
    en += hr * R2[j];
  }
  out_roles[node * 3 + 0] = r0;
  out_roles[node * 3 + 1] = r1;
  out_roles[node * 3 + 2] = r2;
  out_energy[node] = en;
}

extern "C" void kernel_launch(void* const* d_in, const int* in_sizes, int n_in,
                              void* d_out, int out_size, void* d_ws, size_t ws_size,
                              hipStream_t stream) {
  const float* x    = (const float*)d_in[0];
  const int*   ei   = (const int*)d_in[1];
  const float* W1   = (const float*)d_in[2];
  const float* as1w = (const float*)d_in[3];
  const float* ad1w = (const float*)d_in[4];
  const float* b1   = (const float*)d_in[5];
  const float* W2   = (const float*)d_in[6];
  const float* as2w = (const float*)d_in[7];
  const float* ad2w = (const float*)d_in[8];
  const float* b2v  = (const float*)d_in[9];
  const float* bn1g = (const float*)d_in[10];
  const float* bn1b = (const float*)d_in[11];
  const float* bn1m = (const float*)d_in[12];
  const float* bn1v = (const float*)d_in[13];
  const float* bn2g = (const float*)d_in[14];
  const float* bn2b = (const float*)d_in[15];
  const float* bn2m = (const float*)d_in[16];
  const float* bn2v = (const float*)d_in[17];
  const float* cw1  = (const float*)d_in[18];
  const float* cb1  = (const float*)d_in[19];
  const float* cw2  = (const float*)d_in[20];
  const float* cb2  = (const float*)d_in[21];
  const float* rw1  = (const float*)d_in[22];
  const float* rb1  = (const float*)d_in[23];
  const float* rw2  = (const float*)d_in[24];
  const float* rb2  = (const float*)d_in[25];

  // workspace (~57 MB), no aliasing
  uint*  h1u = (uint*)d_ws;               // N*32 uints (bf16x2) = 12.8MB
  float* hbn = (float*)(h1u + NN * 32);   // N*64 f32 = 25.6MB
  float* as1 = hbn + NN * HIDD;           // N*4
  float* ad1 = as1 + NN * NHEADS;         // N*4
  int* rowp  = (int*)(ad1 + NN * NHEADS); // N+1
  int* srcs  = rowp + NN + 1;             // ETOT
  int* bcur  = srcs + ETOT;               // 256
  int* bins  = bcur + 256;                // NBUCK*CAP = 2.0M ints (8MB)
  uint* h2u  = h1u;                       // N*16 uints fits h1u slot (h1 dead)
  float* as2 = as1;
  float* ad2 = ad1;

  float* out        = (float*)d_out;
  float* out_emb    = out;                   // N*32
  float* out_roles  = out + NN * OUTD;       // N*3
  float* out_energy = out + NN * (OUTD + 3); // N*1

  hipMemsetAsync(bcur, 0, NBUCK * sizeof(int), stream);
  k_bin<<<(ETOT + EPB - 1) / EPB, 256, 0, stream>>>(ei, bcur, bins);
  k_csr<<<NBUCK, 256, 0, stream>>>(bcur, bins, rowp, srcs);
  k_lin1<<<NN / 8, 256, 0, stream>>>(x, W1, as1w, ad1w, h1u, as1, ad1);
  k_agg1<<<NN / 8, 256, 0, stream>>>(rowp, srcs, h1u, as1, ad1, b1, bn1g, bn1b, bn1m, bn1v, hbn);
  k_lin2<<<NN / 16, 256, 0, stream>>>(hbn, W2, as2w, ad2w, h2u, as2, ad2);
  k_agg2<<<NN / 4, 256, 0, stream>>>(rowp, srcs, h2u, as2, ad2, b2v, bn2g, bn2b, bn2m, bn2v, out_emb);
  k_mlp<<<(NN + 255) / 256, 256, 0, stream>>>(out_emb, cw1, cb1, cw2, cb2, rw1, rb1, rw2, rb2, out_roles, out_energy);
}

// Round 11
// 326.758 us; speedup vs baseline: 1.1546x; 1.0606x over previous
//
#include <hip/hip_runtime.h>
#include <hip/hip_bf16.h>

#define NN 100000
#define EE 1600000
#define ETOT (EE + NN)          // 1,700,000 edges incl. self-loops
#define IND 32
#define HIDD 64
#define NHEADS 4
#define OUTD 32
#define HID2D 32

#define BSH 8                   // 256 nodes per bucket
#define NBUCK 391               // ceil(NN / 256)
#define CAP 5120                // max edges per bucket (mean ~4348, sigma ~66)
#define EPB 2048                // edges per k_bin block

typedef unsigned int uint;

__device__ __forceinline__ uint pack2(float a, float b) {
  uint lo = (uint)__bfloat16_as_ushort(__float2bfloat16(a));
  uint hi = (uint)__bfloat16_as_ushort(__float2bfloat16(b));
  return (hi << 16) | lo;
}
__device__ __forceinline__ float lo2f(uint w) { return __uint_as_float(w << 16); }
__device__ __forceinline__ float hi2f(uint w) { return __uint_as_float(w & 0xFFFF0000u); }

// ---------- linear 1: h1(bf16) = x @ W1 ; as1/ad1 f32 attention dots ----------
__global__ __launch_bounds__(256) void k_lin1(
    const float* __restrict__ x, const float* __restrict__ W1,
    const float* __restrict__ atsrc, const float* __restrict__ atdst,
    uint* __restrict__ h1u, float* __restrict__ as1, float* __restrict__ ad1) {
  __shared__ float Ws[IND * HIDD];
  __shared__ float xs[8 * IND];
  __shared__ float atS[HIDD], atD[HIDD];
  int t = threadIdx.x;
  for (int i = t; i < IND * HIDD; i += 256) Ws[i] = W1[i];
  if (t < HIDD) { atS[t] = atsrc[t]; atD[t] = atdst[t]; }
  xs[t] = x[blockIdx.x * 256 + t];
  __syncthreads();
  int nl = t >> 5, tl = t & 31;
  int node = blockIdx.x * 8 + nl;
  int j0 = 2 * tl, j1 = j0 + 1;
  float a0 = 0.f, a1 = 0.f;
#pragma unroll
  for (int k = 0; k < IND; k++) {
    float xv = xs[nl * IND + k];
    a0 += xv * Ws[k * HIDD + j0];
    a1 += xv * Ws[k * HIDD + j1];
  }
  h1u[node * 32 + tl] = pack2(a0, a1);
  float ps = a0 * atS[j0] + a1 * atS[j1];
  float pd = a0 * atD[j0] + a1 * atD[j1];
#pragma unroll
  for (int off = 4; off >= 1; off >>= 1) {
    ps += __shfl_down(ps, off, 8);
    pd += __shfl_down(pd, off, 8);
  }
  if ((tl & 7) == 0) {
    as1[node * NHEADS + (tl >> 3)] = ps;
    ad1[node * NHEADS + (tl >> 3)] = pd;
  }
}

// ---------- linear 2: h2(bf16) = hbn(f32) @ W2 ; as2/ad2 ----------
__global__ __launch_bounds__(256) void k_lin2(
    const float* __restrict__ hbn, const float* __restrict__ W2,
    const float* __restrict__ atsrc, const float* __restrict__ atdst,
    uint* __restrict__ h2u, float* __restrict__ as2, float* __restrict__ ad2) {
  __shared__ float Ws[HIDD * OUTD];
  __shared__ float xs[16 * HIDD];
  __shared__ float atS[OUTD], atD[OUTD];
  int t = threadIdx.x;
  for (int i = t; i < HIDD * OUTD; i += 256) Ws[i] = W2[i];
  if (t < OUTD) { atS[t] = atsrc[t]; atD[t] = atdst[t]; }
  for (int i = t; i < 16 * HIDD; i += 256) xs[i] = hbn[blockIdx.x * 16 * HIDD + i];
  __syncthreads();
  int nl = t >> 4, tl = t & 15;
  int node = blockIdx.x * 16 + nl;
  int j0 = 2 * tl, j1 = j0 + 1;
  float a0 = 0.f, a1 = 0.f;
#pragma unroll
  for (int k = 0; k < HIDD; k++) {
    float xv = xs[nl * HIDD + k];
    a0 += xv * Ws[k * OUTD + j0];
    a1 += xv * Ws[k * OUTD + j1];
  }
  h2u[node * 16 + tl] = pack2(a0, a1);
  float ps = a0 * atS[j0] + a1 * atS[j1];
  float pd = a0 * atD[j0] + a1 * atD[j1];
#pragma unroll
  for (int off = 8; off >= 1; off >>= 1) {
    ps += __shfl_down(ps, off, 16);
    pd += __shfl_down(pd, off, 16);
  }
  if (tl == 0) { as2[node] = ps; ad2[node] = pd; }
}

// ---------- pass 1: bucket edges by dst>>8; record = (src<<8)|(dst&255) ----------
__global__ __launch_bounds__(256) void k_bin(const int* __restrict__ ei,
                                             int* __restrict__ bcur,
                                             int* __restrict__ bins) {
  __shared__ int cnt[NBUCK];
  int t = threadIdx.x;
  for (int i = t; i < NBUCK; i += 256) cnt[i] = 0;
  __syncthreads();
  int base = blockIdx.x * EPB;
  int recs[8], bks[8];
#pragma unroll
  for (int k = 0; k < 8; k++) {
    int i = base + k * 256 + t;
    recs[k] = -1; bks[k] = 0;
    if (i < ETOT) {
      int s, d;
      if (i < EE) { s = ei[i]; d = ei[EE + i]; } else { s = i - EE; d = s; }
      recs[k] = (s << BSH) | (d & ((1 << BSH) - 1));
      bks[k] = d >> BSH;
      atomicAdd(&cnt[bks[k]], 1);
    }
  }
  __syncthreads();
  for (int i = t; i < NBUCK; i += 256) cnt[i] = atomicAdd(&bcur[i], cnt[i]);
  __syncthreads();
#pragma unroll
  for (int k = 0; k < 8; k++) {
    if (recs[k] >= 0) {
      int pos = atomicAdd(&cnt[bks[k]], 1);
      bins[bks[k] * CAP + pos] = recs[k];
    }
  }
}

// ---------- pass 2: per-bucket local CSR (391 blocks), inline 512-scan ----------
__global__ __launch_bounds__(256) void k_csr(const int* __restrict__ bcur,
                                             const int* __restrict__ bins,
                                             int* __restrict__ rowp,
                                             int* __restrict__ srcs) {
  __shared__ int lrec[CAP];          // 20KB
  __shared__ int sA[512], sB[512];
  __shared__ int ldeg[256];
  int b = blockIdx.x, t = threadIdx.x;
  // inline exclusive scan of the NBUCK bucket counts (2 elems/thread, 512-scan)
  sA[t] = (t < NBUCK) ? bcur[t] : 0;
  sA[t + 256] = (t + 256 < NBUCK) ? bcur[t + 256] : 0;
  __syncthreads();
  int* in = sA; int* out = sB;
  for (int off = 1; off < 512; off <<= 1) {
    for (int i = t; i < 512; i += 256)
      out[i] = in[i] + ((i >= off) ? in[i - off] : 0);
    __syncthreads();
    int* tmp = in; in = out; out = tmp;
  }
  int gb = (b == 0) ? 0 : in[b - 1];
  if (b == 0 && t == 0) rowp[NN] = ETOT;
  __syncthreads();
  int count = bcur[b]; if (count > CAP) count = CAP;
  ldeg[t] = 0;
  __syncthreads();
  for (int i = t; i < count; i += 256) {
    int r = bins[b * CAP + i];
    lrec[i] = r;
    atomicAdd(&ldeg[r & 255], 1);
  }
  __syncthreads();
  int dv = ldeg[t];
  sA[t] = dv;
  __syncthreads();
  in = sA; out = sB;
  for (int off = 1; off < 256; off <<= 1) {
    out[t] = in[t] + ((t >= off) ? in[t - off] : 0);
    __syncthreads();
    int* tmp = in; in = out; out = tmp;
  }
  int nb = b << BSH;
  int ex = in[t] - dv;               // exclusive scan
  if (nb + t < NN) rowp[nb + t] = gb + ex;
  ldeg[t] = ex;                      // reuse as scatter cursor
  __syncthreads();
  for (int i = t; i < count; i += 256) {
    int r = lrec[i];
    int pos = atomicAdd(&ldeg[r & 255], 1);
    srcs[gb + pos] = r >> BSH;
  }
}

// ---------- GAT1 aggregation + bias + BN1 + ReLU, DUAL-node waves ----------
__global__ __launch_bounds__(256) void k_agg1(
    const int* __restrict__ rowp, const int* __restrict__ srcs,
    const uint* __restrict__ h1u, const float* __restrict__ as1,
    const float* __restrict__ ad1, const float* __restrict__ b1,
    const float* __restrict__ g, const float* __restrict__ bb,
    const float* __restrict__ m, const float* __restrict__ v,
    float* __restrict__ hbn) {
  int t = threadIdx.x;
  int wid = t >> 6, lane = t & 63;
  int nA = blockIdx.x * 8 + wid * 2;
  int nB = nA + 1;
  int slot = lane >> 3;
  int fl = lane & 7;
  int hd = fl >> 1;
  int stA = rowp[nA], eA = rowp[nA + 1], eB = rowp[nB + 1];
  int stB = eA;
  int lpA = eA - 1, lpB = eB - 1;      // deg >= 1 (self-loop)
  float advA = ad1[nA * NHEADS + hd];
  float advB = ad1[nB * NHEADS + hd];
  const uint4* h14 = (const uint4*)h1u;
  float accA[8] = {0,0,0,0,0,0,0,0}, accB[8] = {0,0,0,0,0,0,0,0};
  float lA = 0.f, lB = 0.f;
  int pA = stA + slot, pB = stB + slot;
  int sA0 = srcs[pA < lpA ? pA : lpA];
  int sB0 = srcs[pB < lpB ? pB : lpB];
  uint4 wA = h14[sA0 * 8 + fl];
  uint4 wB = h14[sB0 * 8 + fl];
  float asA = as1[sA0 * NHEADS + hd];
  float asB = as1[sB0 * NHEADS + hd];
  int p1A = pA + 8, p1B = pB + 8;
  int sA1 = srcs[p1A < lpA ? p1A : lpA];
  int sB1 = srcs[p1B < lpB ? p1B : lpB];
  while (pA < eA || pB < eB) {
    uint4 wnA = h14[sA1 * 8 + fl];
    uint4 wnB = h14[sB1 * 8 + fl];
    float anA = as1[sA1 * NHEADS + hd];
    float anB = as1[sB1 * NHEADS + hd];
    int p2A = p1A + 8, p2B = p1B + 8;
    int sA2 = srcs[p2A < lpA ? p2A : lpA];
    int sB2 = srcs[p2B < lpB ? p2B : lpB];
    if (pA < eA) {
      float e = asA + advA;
      e = fmaxf(e, 0.2f * e);
      float ex = __expf(e);
      lA += ex;
      accA[0] += ex * lo2f(wA.x); accA[1] += ex * hi2f(wA.x);
      accA[2] += ex * lo2f(wA.y); accA[3] += ex * hi2f(wA.y);
      accA[4] += ex * lo2f(wA.z); accA[5] += ex * hi2f(wA.z);
      accA[6] += ex * lo2f(wA.w); accA[7] += ex * hi2f(wA.w);
    }
    if (pB < eB) {
      float e = asB + advB;
      e = fmaxf(e, 0.2f * e);
      float ex = __expf(e);
      lB += ex;
      accB[0] += ex * lo2f(wB.x); accB[1] += ex * hi2f(wB.x);
      accB[2] += ex * lo2f(wB.y); accB[3] += ex * hi2f(wB.y);
      accB[4] += ex * lo2f(wB.z); accB[5] += ex * hi2f(wB.z);
      accB[6] += ex * lo2f(wB.w); accB[7] += ex * hi2f(wB.w);
    }
    wA = wnA; wB = wnB; asA = anA; asB = anB;
    sA1 = sA2; sB1 = sB2;
    pA = p1A; pB = p1B; p1A = p2A; p1B = p2B;
  }
#pragma unroll
  for (int off = 8; off <= 32; off <<= 1) {
#pragma unroll
    for (int i = 0; i < 8; i++) {
      accA[i] += __shfl_xor(accA[i], off, 64);
      accB[i] += __shfl_xor(accB[i], off, 64);
    }
    lA += __shfl_xor(lA, off, 64);
    lB += __shfl_xor(lB, off, 64);
  }
  if (slot < 2) {
    int node = slot == 0 ? nA : nB;
    float lsum = slot == 0 ? lA : lB;
    float li = 1.f / (lsum + 1e-16f);
    int fb = fl * 8;
    float o[8];
#pragma unroll
    for (int i = 0; i < 8; i++) {
      int j = fb + i;
      float av = slot == 0 ? accA[i] : accB[i];
      float ov = av * li + b1[j];
      ov = (ov - m[j]) * rsqrtf(v[j] + 1e-5f) * g[j] + bb[j];
      o[i] = fmaxf(ov, 0.f);
    }
    float4* dst = (float4*)(hbn + node * HIDD + fb);
    dst[0] = make_float4(o[0], o[1], o[2], o[3]);
    dst[1] = make_float4(o[4], o[5], o[6], o[7]);
  }
}

// ---------- GAT2 aggregation + bias + BN2 + ReLU, DUAL-node waves ----------
// wave per 2 nodes; 8 edge slots x 8 lanes; lane reads uint2 = 4 bf16 feats.
__global__ __launch_bounds__(256) void k_agg2(
    const int* __restrict__ rowp, const int* __restrict__ srcs,
    const uint* __restrict__ h2u, const float* __restrict__ as2,
    const float* __restrict__ ad2, const float* __restrict__ b2v,
    const float* __restrict__ g, const float* __restrict__ bb,
    const float* __restrict__ m, const float* __restrict__ v,
    float* __restrict__ out_emb) {
  int t = threadIdx.x;
  int wid = t >> 6, lane = t & 63;
  int nA = blockIdx.x * 8 + wid * 2;
  int nB = nA + 1;
  int slot = lane >> 3;
  int fl = lane & 7;         // feats fl*4..fl*4+3
  int stA = rowp[nA], eA = rowp[nA + 1], eB = rowp[nB + 1];
  int stB = eA;
  int lpA = eA - 1, lpB = eB - 1;
  float advA = ad2[nA], advB = ad2[nB];
  const uint2* h22 = (const uint2*)h2u;
  float accA[4] = {0,0,0,0}, accB[4] = {0,0,0,0};
  float lA = 0.f, lB = 0.f;
  int pA = stA + slot, pB = stB + slot;
  int sA0 = srcs[pA < lpA ? pA : lpA];
  int sB0 = srcs[pB < lpB ? pB : lpB];
  uint2 wA = h22[sA0 * 8 + fl];
  uint2 wB = h22[sB0 * 8 + fl];
  float asA = as2[sA0], asB = as2[sB0];
  int p1A = pA + 8, p1B = pB + 8;
  int sA1 = srcs[p1A < lpA ? p1A : lpA];
  int sB1 = srcs[p1B < lpB ? p1B : lpB];
  while (pA < eA || pB < eB) {
    uint2 wnA = h22[sA1 * 8 + fl];
    uint2 wnB = h22[sB1 * 8 + fl];
    float anA = as2[sA1], anB = as2[sB1];
    int p2A = p1A + 8, p2B = p1B + 8;
    int sA2 = srcs[p2A < lpA ? p2A : lpA];
    int sB2 = srcs[p2B < lpB ? p2B : lpB];
    if (pA < eA) {
      float e = asA + advA;
      e = fmaxf(e, 0.2f * e);
      float ex = __expf(e);
      lA += ex;
      accA[0] += ex * lo2f(wA.x); accA[1] += ex * hi2f(wA.x);
      accA[2] += ex * lo2f(wA.y); accA[3] += ex * hi2f(wA.y);
    }
    if (pB < eB) {
      float e = asB + advB;
      e = fmaxf(e, 0.2f * e);
      float ex = __expf(e);
      lB += ex;
      accB[0] += ex * lo2f(wB.x); accB[1] += ex * hi2f(wB.x);
      accB[2] += ex * lo2f(wB.y); accB[3] += ex * hi2f(wB.y);
    }
    wA = wnA; wB = wnB; asA = anA; asB = anB;
    sA1 = sA2; sB1 = sB2;
    pA = p1A; pB = p1B; p1A = p2A; p1B = p2B;
  }
#pragma unroll
  for (int off = 8; off <= 32; off <<= 1) {
#pragma unroll
    for (int i = 0; i < 4; i++) {
      accA[i] += __shfl_xor(accA[i], off, 64);
      accB[i] += __shfl_xor(accB[i], off, 64);
    }
    lA += __shfl_xor(lA, off, 64);
    lB += __shfl_xor(lB, off, 64);
  }
  if (slot < 2) {
    int node = slot == 0 ? nA : nB;
    float lsum = slot == 0 ? lA : lB;
    float li = 1.f / (lsum + 1e-16f);
    int fb = fl * 4;
    float o[4];
#pragma unroll
    for (int i = 0; i < 4; i++) {
      int j = fb + i;
      float av = slot == 0 ? accA[i] : accB[i];
      float ov = av * li + b2v[j];
      ov = (ov - m[j]) * rsqrtf(v[j] + 1e-5f) * g[j] + bb[j];
      o[i] = fmaxf(ov, 0.f);
    }
    *(float4*)(out_emb + node * OUTD + fb) = make_float4(o[0], o[1], o[2], o[3]);
  }
}

// ---------- classifier + regressor heads (thread per node) ----------
__global__ __launch_bounds__(256) void k_mlp(
    const float* __restrict__ embf,
    const float* __restrict__ cw1, const float* __restrict__ cb1,
    const float* __restrict__ cw2, const float* __restrict__ cb2,
    const float* __restrict__ rw1, const float* __restrict__ rb1,
    const float* __restrict__ rw2, const float* __restrict__ rb2,
    float* __restrict__ out_roles, float* __restrict__ out_energy) {
  __shared__ float C1[OUTD * HID2D], R1[OUTD * HID2D];
  __shared__ float C2[HID2D * 3], CB1[HID2D], RB1[HID2D], R2[HID2D];
  __shared__ float CB2v[3], RB2v;
  int t = threadIdx.x;
  for (int i = t; i < OUTD * HID2D; i += 256) { C1[i] = cw1[i]; R1[i] = rw1[i]; }
  if (t < HID2D) { CB1[t] = cb1[t]; RB1[t] = rb1[t]; R2[t] = rw2[t]; }
  if (t < HID2D * 3) C2[t] = cw2[t];
  if (t < 3) CB2v[t] = cb2[t];
  if (t == 0) RB2v = rb2[0];
  __syncthreads();
  int node = blockIdx.x * 256 + t;
  if (node >= NN) return;
  float e[OUTD];
#pragma unroll
  for (int k = 0; k < OUTD; k++) e[k] = embf[node * OUTD + k];
  float r0 = CB2v[0], r1 = CB2v[1], r2 = CB2v[2], en = RB2v;
  for (int j = 0; j < HID2D; j++) {
    float hc = CB1[j], hr = RB1[j];
#pragma unroll
    for (int k = 0; k < OUTD; k++) {
      hc += e[k] * C1[k * HID2D + j];
      hr += e[k] * R1[k * HID2D + j];
    }
    hc = fmaxf(hc, 0.f);
    hr = fmaxf(hr, 0.f);
    r0 += hc * C2[j * 3 + 0];
    r1 += hc * C2[j * 3 + 1];
    r2 += hc * C2[j * 3 + 2];
    en += hr * R2[j];
  }
  out_roles[node * 3 + 0] = r0;
  out_roles[node * 3 + 1] = r1;
  out_roles[node * 3 + 2] = r2;
  out_energy[node] = en;
}

extern "C" void kernel_launch(void* const* d_in, const int* in_sizes, int n_in,
                              void* d_out, int out_size, void* d_ws, size_t ws_size,
                              hipStream_t stream) {
  const float* x    = (const float*)d_in[0];
  const int*   ei   = (const int*)d_in[1];
  const float* W1   = (const float*)d_in[2];
  const float* as1w = (const float*)d_in[3];
  const float* ad1w = (const float*)d_in[4];
  const float* b1   = (const float*)d_in[5];
  const float* W2   = (const float*)d_in[6];
  const float* as2w = (const float*)d_in[7];
  const float* ad2w = (const float*)d_in[8];
  const float* b2v  = (const float*)d_in[9];
  const float* bn1g = (const float*)d_in[10];
  const float* bn1b = (const float*)d_in[11];
  const float* bn1m = (const float*)d_in[12];
  const float* bn1v = (const float*)d_in[13];
  const float* bn2g = (const float*)d_in[14];
  const float* bn2b = (const float*)d_in[15];
  const float* bn2m = (const float*)d_in[16];
  const float* bn2v = (const float*)d_in[17];
  const float* cw1  = (const float*)d_in[18];
  const float* cb1  = (const float*)d_in[19];
  const float* cw2  = (const float*)d_in[20];
  const float* cb2  = (const float*)d_in[21];
  const float* rw1  = (const float*)d_in[22];
  const float* rb1  = (const float*)d_in[23];
  const float* rw2  = (const float*)d_in[24];
  const float* rb2  = (const float*)d_in[25];

  // workspace (~56 MB), no aliasing
  uint*  h1u = (uint*)d_ws;               // N*32 uints (bf16x2) = 12.8MB
  float* hbn = (float*)(h1u + NN * 32);   // N*64 f32 = 25.6MB
  float* as1 = hbn + NN * HIDD;           // N*4
  float* ad1 = as1 + NN * NHEADS;         // N*4
  int* rowp  = (int*)(ad1 + NN * NHEADS); // N+1
  int* srcs  = rowp + NN + 1;             // ETOT
  int* bcur  = srcs + ETOT;               // 512
  int* bins  = bcur + 512;                // NBUCK*CAP = 2.0M ints (8MB)
  uint* h2u  = h1u;                       // N*16 uints fits h1u slot (h1 dead)
  float* as2 = as1;
  float* ad2 = ad1;

  float* out        = (float*)d_out;
  float* out_emb    = out;                   // N*32
  float* out_roles  = out + NN * OUTD;       // N*3
  float* out_energy = out + NN * (OUTD + 3); // N*1

  hipMemsetAsync(bcur, 0, 512 * sizeof(int), stream);
  k_bin<<<(ETOT + EPB - 1) / EPB, 256, 0, stream>>>(ei, bcur, bins);
  k_csr<<<NBUCK, 256, 0, stream>>>(bcur, bins, rowp, srcs);
  k_lin1<<<NN / 8, 256, 0, stream>>>(x, W1, as1w, ad1w, h1u, as1, ad1);
  k_agg1<<<NN / 8, 256, 0, stream>>>(rowp, srcs, h1u, as1, ad1, b1, bn1g, bn1b, bn1m, bn1v, hbn);
  k_lin2<<<NN / 16, 256, 0, stream>>>(hbn, W2, as2w, ad2w, h2u, as2, ad2);
  k_agg2<<<NN / 8, 256, 0, stream>>>(rowp, srcs, h2u, as2, ad2, b2v, bn2g, bn2b, bn2m, bn2v, out_emb);
  k_mlp<<<(NN + 255) / 256, 256, 0, stream>>>(out_emb, cw1, cb1, cw2, cb2, rw1, rb1, rw2, rb2, out_roles, out_energy);
}